// Round 1
// baseline (590.384 us; speedup 1.0000x reference)
//
#include <hip/hip_runtime.h>
#include <hip/hip_bf16.h>

typedef __bf16 bf16x8 __attribute__((ext_vector_type(8)));
typedef float f32x4 __attribute__((ext_vector_type(4)));
typedef unsigned short u16x8 __attribute__((ext_vector_type(8)));
typedef unsigned short u16x4 __attribute__((ext_vector_type(4)));

#define EPS 1e-8f
#define TAU_INV 10.0f

#define BM 64
#define BN 512
#define BK 32
#define SA_STRIDE 40   // 32 + 8 pad: keeps ds_read_b128 16B-aligned, 2-way banks (free)
#define SB_STRIDE 40
#define LSTRIDE 516    // 512 + 4 pad for epilogue fp32 tile

// ---------------------------------------------------------------------------
// prep: per-row inverse norm (fp32, matches reference) + fp32->bf16 convert
// one wave per row; rows [0,N) = embeddings, [N,N+K) = centers
// ---------------------------------------------------------------------------
__global__ __launch_bounds__(256) void prep_kernel(
    const float* __restrict__ emb, const float* __restrict__ cen,
    unsigned short* __restrict__ Abf, unsigned short* __restrict__ Bbf,
    float* __restrict__ inv_e, float* __restrict__ inv_c,
    int N, int K, int D)
{
    const int wave = threadIdx.x >> 6;
    const int lane = threadIdx.x & 63;
    const int row  = blockIdx.x * 4 + wave;
    if (row >= N + K) return;

    const float* src;
    unsigned short* dst;
    if (row < N) { src = emb + (size_t)row * D;       dst = Abf + (size_t)row * D; }
    else         { src = cen + (size_t)(row - N) * D; dst = Bbf + (size_t)(row - N) * D; }

    float ss = 0.0f;
    const int nvec = D >> 2;
    const float4* s4 = (const float4*)src;
    for (int i = lane; i < nvec; i += 64) {
        float4 v = s4[i];
        ss += v.x * v.x + v.y * v.y + v.z * v.z + v.w * v.w;
        u16x4 u;
        u[0] = __builtin_bit_cast(unsigned short, __float2bfloat16(v.x));
        u[1] = __builtin_bit_cast(unsigned short, __float2bfloat16(v.y));
        u[2] = __builtin_bit_cast(unsigned short, __float2bfloat16(v.z));
        u[3] = __builtin_bit_cast(unsigned short, __float2bfloat16(v.w));
        *(u16x4*)(dst + (size_t)i * 4) = u;
    }
    #pragma unroll
    for (int off = 32; off; off >>= 1) ss += __shfl_xor(ss, off);

    if (lane == 0) {
        float inv = 1.0f / fmaxf(sqrtf(ss), EPS);
        if (row < N) inv_e[row] = inv;
        else         inv_c[row - N] = inv * TAU_INV;  // fold 1/tau into center scale
    }
}

// ---------------------------------------------------------------------------
// fused GEMM + log-softmax + NLL: each block = 64 rows x all 512 centers
// 512 threads = 8 waves; wave w owns cols [w*64, w*64+64), all 64 rows
// ---------------------------------------------------------------------------
__global__ __launch_bounds__(512) void gemm_loss_kernel(
    const unsigned short* __restrict__ Abf, const unsigned short* __restrict__ Bbf,
    const float* __restrict__ inv_e, const float* __restrict__ inv_c,
    const int* __restrict__ labels, float* __restrict__ out,
    int N, int D)
{
    __shared__ union {
        struct {
            unsigned short A[BM * SA_STRIDE];  // 5120 B
            unsigned short B[BN * SB_STRIDE];  // 40960 B
        } t;
        float L[16 * LSTRIDE];                 // 33024 B (epilogue reuse)
    } sm;
    __shared__ float blockLoss;

    const int tid  = threadIdx.x;
    const int wave = tid >> 6;
    const int lane = tid & 63;
    const int quad = lane >> 4;
    const int tq   = lane & 15;
    const int blockRow = blockIdx.x * BM;

    f32x4 acc[4][4];
    #pragma unroll
    for (int mt = 0; mt < 4; ++mt)
        #pragma unroll
        for (int nt = 0; nt < 4; ++nt)
            acc[mt][nt] = (f32x4){0.f, 0.f, 0.f, 0.f};

    if (tid == 0) blockLoss = 0.0f;

    // staging index precompute
    const int a_row = tid >> 2;           // 0..127 (only tid<256 stages A: rows 0..63)
    const int a_kl  = (tid & 3) * 8;      // 0,8,16,24

    const int nK = D / BK;
    for (int kt = 0; kt < nK; ++kt) {
        __syncthreads();
        // ---- stage A: 64x32 bf16 (threads 0..255, one u16x8 each) ----
        if (tid < 256) {
            u16x8 v = *(const u16x8*)(Abf + (size_t)(blockRow + a_row) * D + kt * BK + a_kl);
            *(u16x8*)(&sm.t.A[a_row * SA_STRIDE + a_kl]) = v;
        }
        // ---- stage B: 512x32 bf16 (4 u16x8 per thread) ----
        u16x8 bv[4];
        #pragma unroll
        for (int c = 0; c < 4; ++c) {
            int row = c * 128 + (tid >> 2);
            bv[c] = *(const u16x8*)(Bbf + (size_t)row * D + kt * BK + a_kl);
        }
        #pragma unroll
        for (int c = 0; c < 4; ++c) {
            int row = c * 128 + (tid >> 2);
            *(u16x8*)(&sm.t.B[row * SB_STRIDE + a_kl]) = bv[c];
        }
        __syncthreads();

        // ---- MFMA: 4x4 tiles of 16x16, K=32 consumed per step ----
        bf16x8 af[4], bfv[4];
        #pragma unroll
        for (int mt = 0; mt < 4; ++mt)
            af[mt] = *(const bf16x8*)(&sm.t.A[(mt * 16 + tq) * SA_STRIDE + quad * 8]);
        #pragma unroll
        for (int nt = 0; nt < 4; ++nt)
            bfv[nt] = *(const bf16x8*)(&sm.t.B[(wave * 64 + nt * 16 + tq) * SB_STRIDE + quad * 8]);
        #pragma unroll
        for (int mt = 0; mt < 4; ++mt)
            #pragma unroll
            for (int nt = 0; nt < 4; ++nt)
                acc[mt][nt] = __builtin_amdgcn_mfma_f32_16x16x32_bf16(
                    af[mt], bfv[nt], acc[mt][nt], 0, 0, 0);
    }

    // ---- epilogue: scale, then per-16-row groups: logsumexp + NLL ----
    float ie[4][4];
    #pragma unroll
    for (int mt = 0; mt < 4; ++mt)
        #pragma unroll
        for (int r = 0; r < 4; ++r)
            ie[mt][r] = inv_e[blockRow + mt * 16 + quad * 4 + r];
    float ic[4];
    #pragma unroll
    for (int nt = 0; nt < 4; ++nt)
        ic[nt] = inv_c[wave * 64 + nt * 16 + tq];

    const float invN = 1.0f / (float)N;

    for (int g = 0; g < 4; ++g) {
        __syncthreads();
        // write this group's 16x512 scaled logits to LDS
        #pragma unroll
        for (int nt = 0; nt < 4; ++nt) {
            int col = wave * 64 + nt * 16 + tq;
            #pragma unroll
            for (int r = 0; r < 4; ++r) {
                float v = acc[g][nt][r] * ie[g][r] * ic[nt];
                sm.L[(quad * 4 + r) * LSTRIDE + col] = v;
            }
        }
        __syncthreads();
        // each wave reduces 2 rows (8 waves x 2 = 16 rows)
        #pragma unroll
        for (int rr = 0; rr < 2; ++rr) {
            int rl = wave * 2 + rr;
            int grow = blockRow + g * 16 + rl;
            float vals[8];
            float vmax = -3.0e38f;
            #pragma unroll
            for (int j = 0; j < 8; ++j) {
                vals[j] = sm.L[rl * LSTRIDE + j * 64 + lane];
                vmax = fmaxf(vmax, vals[j]);
            }
            #pragma unroll
            for (int off = 32; off; off >>= 1) vmax = fmaxf(vmax, __shfl_xor(vmax, off));
            float s = 0.0f;
            #pragma unroll
            for (int j = 0; j < 8; ++j) s += __expf(vals[j] - vmax);
            #pragma unroll
            for (int off = 32; off; off >>= 1) s += __shfl_xor(s, off);
            if (lane == 0) {
                int lab = labels[grow];
                float ll = sm.L[rl * LSTRIDE + lab];
                atomicAdd(&blockLoss, vmax + __logf(s) - ll);
            }
        }
    }
    __syncthreads();
    if (tid == 0) atomicAdd(out, blockLoss * invN);
}

// ---------------------------------------------------------------------------
extern "C" void kernel_launch(void* const* d_in, const int* in_sizes, int n_in,
                              void* d_out, int out_size, void* d_ws, size_t ws_size,
                              hipStream_t stream)
{
    const float* emb = (const float*)d_in[0];
    const float* cen = (const float*)d_in[1];
    const int* labels = (const int*)d_in[2];
    float* out = (float*)d_out;

    const int N = in_sizes[2];
    const int D = in_sizes[0] / N;
    const int K = in_sizes[1] / D;

    // workspace layout
    char* ws = (char*)d_ws;
    unsigned short* Abf = (unsigned short*)ws;                       // N*D*2
    unsigned short* Bbf = (unsigned short*)(ws + (size_t)N * D * 2); // K*D*2
    float* inv_e = (float*)(ws + (size_t)N * D * 2 + (size_t)K * D * 2);
    float* inv_c = inv_e + N;

    hipMemsetAsync(d_out, 0, sizeof(float), stream);

    int prep_blocks = (N + K + 3) / 4;
    prep_kernel<<<prep_blocks, 256, 0, stream>>>(emb, cen, Abf, Bbf, inv_e, inv_c, N, K, D);

    int gemm_blocks = N / BM;
    gemm_loss_kernel<<<gemm_blocks, 512, 0, stream>>>(Abf, Bbf, inv_e, inv_c, labels, out, N, D);
}

// Round 2
// 493.802 us; speedup vs baseline: 1.1956x; 1.1956x over previous
//
#include <hip/hip_runtime.h>
#include <hip/hip_bf16.h>

typedef __bf16 bf16x8 __attribute__((ext_vector_type(8)));
typedef float f32x4 __attribute__((ext_vector_type(4)));
typedef unsigned short u16x4 __attribute__((ext_vector_type(4)));

#define EPS 1e-8f
#define TAU_INV 10.0f

#define BM 64
#define BN 512
#define BK 32
#define MT_TILES 4    // BM/16
#define NT_TILES 32   // BN/16
#define LSTRIDE 516   // 512 + 4 pad for epilogue fp32 tile

// async global->LDS, 16B per lane, dest = wave-uniform base + lane*16
__device__ __forceinline__ void gload_lds16(const void* g, void* l) {
    __builtin_amdgcn_global_load_lds(
        (const __attribute__((address_space(1))) void*)g,
        (__attribute__((address_space(3))) void*)l,
        16, 0, 0);
}

// ---------------------------------------------------------------------------
// prep: centers only (K=512): fp32 norm + bf16 convert. ~3 us.
// ---------------------------------------------------------------------------
__global__ __launch_bounds__(256) void prep_centers_kernel(
    const float* __restrict__ cen, unsigned short* __restrict__ Bbf,
    float* __restrict__ inv_c, int K, int D)
{
    const int wave = threadIdx.x >> 6;
    const int lane = threadIdx.x & 63;
    const int row  = blockIdx.x * 4 + wave;
    if (row >= K) return;

    const float* src = cen + (size_t)row * D;
    unsigned short* dst = Bbf + (size_t)row * D;

    float ss = 0.0f;
    const int nvec = D >> 2;
    const float4* s4 = (const float4*)src;
    for (int i = lane; i < nvec; i += 64) {
        float4 v = s4[i];
        ss += v.x * v.x + v.y * v.y + v.z * v.z + v.w * v.w;
        u16x4 u;
        u[0] = __builtin_bit_cast(unsigned short, __float2bfloat16(v.x));
        u[1] = __builtin_bit_cast(unsigned short, __float2bfloat16(v.y));
        u[2] = __builtin_bit_cast(unsigned short, __float2bfloat16(v.z));
        u[3] = __builtin_bit_cast(unsigned short, __float2bfloat16(v.w));
        *(u16x4*)(dst + (size_t)i * 4) = u;
    }
    #pragma unroll
    for (int off = 32; off; off >>= 1) ss += __shfl_xor(ss, off);
    if (lane == 0)
        inv_c[row] = (1.0f / fmaxf(sqrtf(ss), EPS)) * TAU_INV; // fold 1/tau
}

// ---------------------------------------------------------------------------
// fused: A fp32->bf16 convert + row norms + GEMM + log-softmax + NLL
// block = 64 rows x all 512 centers; 512 threads = 8 waves.
// LDS layout: lane-major MFMA granules (16B per lane slot) -> conflict-free
// ds_read_b128 @ base + lane*16; B staged via global_load_lds (same layout).
// ---------------------------------------------------------------------------
__global__ __launch_bounds__(512) void gemm_loss_kernel(
    const float* __restrict__ Afp, const unsigned short* __restrict__ Bbf,
    const float* __restrict__ inv_c, const int* __restrict__ labels,
    float* __restrict__ out, int N, int D)
{
    __shared__ union {
        struct {
            unsigned short A[MT_TILES * 512];  // 4 tiles * 64 granules * 8 u16 = 4KB
            unsigned short B[NT_TILES * 512];  // 32KB
        } t;
        float L[16 * LSTRIDE];                 // 33KB epilogue reuse
    } sm;
    __shared__ float inv_e_s[BM];
    __shared__ float blockLoss;

    const int tid  = threadIdx.x;
    const int wave = tid >> 6;
    const int lane = tid & 63;
    const int quad = lane >> 4;
    const int tq   = lane & 15;
    const int blockRow = blockIdx.x * BM;

    // ---- A staging mapping: thread t owns (row=t>>3, k-slice=(t&7)*4) ----
    const int ar   = tid >> 3;        // 0..63
    const int aj   = tid & 7;         // 0..7 -> 4 floats each
    const int a_mt = ar >> 4, a_r16 = ar & 15;
    const int a_q  = aj >> 1, a_jl = aj & 1;
    // XOR swizzle keeps VGPR b64 writes conflict-free; reads stay lane*16
    const int a_wslot = (a_r16 ^ (2 * a_q)) + a_q * 16;
    unsigned short* a_wr = &sm.t.A[a_mt * 512 + a_wslot * 8 + a_jl * 4];
    const float* ag = Afp + (size_t)(blockRow + ar) * D + aj * 4;

    // ---- B staging: wave w DMAs its own 4 nt-tiles ----
    const unsigned short* bg[4];
    unsigned short* b_dst[4];
    #pragma unroll
    for (int i = 0; i < 4; ++i) {
        int nt = wave * 4 + i;
        bg[i]    = Bbf + (size_t)(nt * 16 + tq) * D + quad * 8;
        b_dst[i] = &sm.t.B[nt * 512];   // wave-uniform base
    }

    // ---- fragment read addresses (kt-invariant) ----
    const int a_rslot = (tq ^ (2 * quad)) + quad * 16;
    const unsigned short* a_rd[4];
    const unsigned short* b_rd[4];
    #pragma unroll
    for (int mt = 0; mt < 4; ++mt) a_rd[mt] = &sm.t.A[mt * 512 + a_rslot * 8];
    #pragma unroll
    for (int i = 0; i < 4; ++i)    b_rd[i]  = &sm.t.B[(wave * 4 + i) * 512 + lane * 8];

    f32x4 acc[4][4];
    #pragma unroll
    for (int mt = 0; mt < 4; ++mt)
        #pragma unroll
        for (int nt = 0; nt < 4; ++nt)
            acc[mt][nt] = (f32x4){0.f, 0.f, 0.f, 0.f};
    float ssq = 0.0f;
    if (tid == 0) blockLoss = 0.0f;

    const int nK = D / BK;
    for (int kt = 0; kt < nK; ++kt) {
        __syncthreads();  // previous iter's frag reads done before overwrite
        // B: async DMA straight into fragment layout
        #pragma unroll
        for (int i = 0; i < 4; ++i)
            gload_lds16(bg[i] + kt * BK, b_dst[i]);
        // A: fp32 load (coalesced 128B segments) + sumsq + convert + LDS
        float4 v = *(const float4*)(ag + kt * BK);
        ssq += v.x * v.x + v.y * v.y + v.z * v.z + v.w * v.w;
        u16x4 u;
        u[0] = __builtin_bit_cast(unsigned short, __float2bfloat16(v.x));
        u[1] = __builtin_bit_cast(unsigned short, __float2bfloat16(v.y));
        u[2] = __builtin_bit_cast(unsigned short, __float2bfloat16(v.z));
        u[3] = __builtin_bit_cast(unsigned short, __float2bfloat16(v.w));
        *(u16x4*)a_wr = u;
        __syncthreads();  // drains vmcnt (DMA) + lgkmcnt (A writes)

        bf16x8 af[4], bfv[4];
        #pragma unroll
        for (int mt = 0; mt < 4; ++mt) af[mt]  = *(const bf16x8*)a_rd[mt];
        #pragma unroll
        for (int i = 0; i < 4; ++i)    bfv[i]  = *(const bf16x8*)b_rd[i];
        #pragma unroll
        for (int mt = 0; mt < 4; ++mt)
            #pragma unroll
            for (int nt = 0; nt < 4; ++nt)
                acc[mt][nt] = __builtin_amdgcn_mfma_f32_16x16x32_bf16(
                    af[mt], bfv[nt], acc[mt][nt], 0, 0, 0);
    }

    // ---- row inverse norms: reduce 8 k-slice partials per row ----
    ssq += __shfl_xor(ssq, 1);
    ssq += __shfl_xor(ssq, 2);
    ssq += __shfl_xor(ssq, 4);
    if (aj == 0) inv_e_s[ar] = 1.0f / fmaxf(sqrtf(ssq), EPS);

    // ---- epilogue: scale + per-16-row logsumexp + NLL ----
    float ic[4];
    #pragma unroll
    for (int nt = 0; nt < 4; ++nt)
        ic[nt] = inv_c[wave * 64 + nt * 16 + tq];
    const float invN = 1.0f / (float)N;

    for (int g = 0; g < 4; ++g) {
        __syncthreads();
        float ie[4];
        #pragma unroll
        for (int r = 0; r < 4; ++r)
            ie[r] = inv_e_s[g * 16 + quad * 4 + r];
        #pragma unroll
        for (int nt = 0; nt < 4; ++nt) {
            int col = wave * 64 + nt * 16 + tq;
            #pragma unroll
            for (int r = 0; r < 4; ++r)
                sm.L[(quad * 4 + r) * LSTRIDE + col] = acc[g][nt][r] * ie[r] * ic[nt];
        }
        __syncthreads();
        #pragma unroll
        for (int rr = 0; rr < 2; ++rr) {
            int rl = wave * 2 + rr;
            int grow = blockRow + g * 16 + rl;
            float vals[8];
            float vmax = -3.0e38f;
            #pragma unroll
            for (int j = 0; j < 8; ++j) {
                vals[j] = sm.L[rl * LSTRIDE + j * 64 + lane];
                vmax = fmaxf(vmax, vals[j]);
            }
            #pragma unroll
            for (int off = 32; off; off >>= 1) vmax = fmaxf(vmax, __shfl_xor(vmax, off));
            float s = 0.0f;
            #pragma unroll
            for (int j = 0; j < 8; ++j) s += __expf(vals[j] - vmax);
            #pragma unroll
            for (int off = 32; off; off >>= 1) s += __shfl_xor(s, off);
            if (lane == 0) {
                int lab = labels[grow];
                float ll = sm.L[rl * LSTRIDE + lab];
                atomicAdd(&blockLoss, vmax + __logf(s) - ll);
            }
        }
    }
    __syncthreads();
    if (tid == 0) atomicAdd(out, blockLoss * invN);
}

// ---------------------------------------------------------------------------
extern "C" void kernel_launch(void* const* d_in, const int* in_sizes, int n_in,
                              void* d_out, int out_size, void* d_ws, size_t ws_size,
                              hipStream_t stream)
{
    const float* emb = (const float*)d_in[0];
    const float* cen = (const float*)d_in[1];
    const int* labels = (const int*)d_in[2];
    float* out = (float*)d_out;

    const int N = in_sizes[2];
    const int D = in_sizes[0] / N;
    const int K = in_sizes[1] / D;

    char* ws = (char*)d_ws;
    unsigned short* Bbf = (unsigned short*)ws;              // K*D*2 bytes
    float* inv_c = (float*)(ws + (size_t)K * D * 2);        // K floats

    hipMemsetAsync(d_out, 0, sizeof(float), stream);

    prep_centers_kernel<<<(K + 3) / 4, 256, 0, stream>>>(cen, Bbf, inv_c, K, D);

    gemm_loss_kernel<<<N / BM, 512, 0, stream>>>(emb, Bbf, inv_c, labels, out, N, D);
}

// Round 3
// 485.231 us; speedup vs baseline: 1.2167x; 1.0177x over previous
//
#include <hip/hip_runtime.h>
#include <hip/hip_bf16.h>

typedef __bf16 bf16x8 __attribute__((ext_vector_type(8)));
typedef float f32x4 __attribute__((ext_vector_type(4)));
typedef unsigned short u16x4 __attribute__((ext_vector_type(4)));

#define EPS 1e-8f
#define TAU_INV 10.0f

#define BM 64
#define BN 512
#define BK 32
#define LSTRIDE 516    // 512 + 4 pad for epilogue fp32 tile

#define ABUF 2048                // u16: 4 tiles * 512
#define BBUF 16384               // u16: 32 tiles * 512
#define BUFSZ (ABUF + BBUF)      // 18432 u16 = 36 KB per buffer

// async global->LDS, 16B per lane, dest = wave-uniform base + lane*16
__device__ __forceinline__ void gload_lds16(const void* g, void* l) {
    __builtin_amdgcn_global_load_lds(
        (const __attribute__((address_space(1))) void*)g,
        (__attribute__((address_space(3))) void*)l,
        16, 0, 0);
}

// ---------------------------------------------------------------------------
// prep: centers only (K=512): fp32 norm + bf16 convert. ~5 us.
// ---------------------------------------------------------------------------
__global__ __launch_bounds__(256) void prep_centers_kernel(
    const float* __restrict__ cen, unsigned short* __restrict__ Bbf,
    float* __restrict__ inv_c, int K, int D)
{
    const int wave = threadIdx.x >> 6;
    const int lane = threadIdx.x & 63;
    const int row  = blockIdx.x * 4 + wave;
    if (row >= K) return;

    const float* src = cen + (size_t)row * D;
    unsigned short* dst = Bbf + (size_t)row * D;

    float ss = 0.0f;
    const int nvec = D >> 2;
    const float4* s4 = (const float4*)src;
    for (int i = lane; i < nvec; i += 64) {
        float4 v = s4[i];
        ss += v.x * v.x + v.y * v.y + v.z * v.z + v.w * v.w;
        u16x4 u;
        u[0] = __builtin_bit_cast(unsigned short, __float2bfloat16(v.x));
        u[1] = __builtin_bit_cast(unsigned short, __float2bfloat16(v.y));
        u[2] = __builtin_bit_cast(unsigned short, __float2bfloat16(v.z));
        u[3] = __builtin_bit_cast(unsigned short, __float2bfloat16(v.w));
        *(u16x4*)(dst + (size_t)i * 4) = u;
    }
    #pragma unroll
    for (int off = 32; off; off >>= 1) ss += __shfl_xor(ss, off);
    if (lane == 0)
        inv_c[row] = (1.0f / fmaxf(sqrtf(ss), EPS)) * TAU_INV; // fold 1/tau
}

// ---------------------------------------------------------------------------
// fused GEMM + log-softmax + NLL, double-buffered LDS, 1 barrier per K-step.
// block = 64 rows x all 512 centers; 512 threads = 8 waves.
// ---------------------------------------------------------------------------
__global__ __launch_bounds__(512, 4) void gemm_loss_kernel(
    const float* __restrict__ Afp, const unsigned short* __restrict__ Bbf,
    const float* __restrict__ inv_c, const int* __restrict__ labels,
    float* __restrict__ out, int N, int D)
{
    __shared__ union {
        unsigned short t[2 * BUFSZ];   // [buf][A(4KB) | B(32KB)]
        float L[16 * LSTRIDE];         // epilogue overlay (33 KB)
    } sm;
    __shared__ float inv_e_s[BM];
    __shared__ float blockLoss;

    const int tid  = threadIdx.x;
    const int wave = tid >> 6;
    const int lane = tid & 63;
    const int quad = lane >> 4;
    const int tq   = lane & 15;
    const int blockRow = blockIdx.x * BM;

    // ---- A staging map: thread owns (row=tid>>3, float4 slice aj=tid&7) ----
    const int ar   = tid >> 3;        // 0..63
    const int aj   = tid & 7;         // 0..7
    const int a_mt = ar >> 4, a_r16 = ar & 15;
    const int a_q  = aj >> 1, a_jl = aj & 1;
    const int a_woff = a_mt * 512 + ((a_r16 ^ (2 * a_q)) + a_q * 16) * 8 + a_jl * 4;
    const float* ag = Afp + (size_t)(blockRow + ar) * D + aj * 4;

    // ---- B staging: wave w DMAs its own 4 nt-tiles ----
    const unsigned short* bg[4];
    int b_off[4];
    #pragma unroll
    for (int i = 0; i < 4; ++i) {
        int nt = wave * 4 + i;
        bg[i]    = Bbf + (size_t)(nt * 16 + tq) * D + quad * 8;
        b_off[i] = ABUF + nt * 512;       // wave-uniform LDS offset (u16)
    }

    // ---- fragment read offsets (buffer-relative, kt-invariant) ----
    const int a_rslot = (tq ^ (2 * quad)) + quad * 16;
    int a_roff[4], b_roff[4];
    #pragma unroll
    for (int mt = 0; mt < 4; ++mt) a_roff[mt] = mt * 512 + a_rslot * 8;
    #pragma unroll
    for (int i = 0; i < 4; ++i)    b_roff[i]  = ABUF + (wave * 4 + i) * 512 + lane * 8;

    f32x4 acc[4][4];
    #pragma unroll
    for (int mt = 0; mt < 4; ++mt)
        #pragma unroll
        for (int nt = 0; nt < 4; ++nt)
            acc[mt][nt] = (f32x4){0.f, 0.f, 0.f, 0.f};
    float ssq = 0.0f;
    if (tid == 0) blockLoss = 0.0f;

    const int nK = D / BK;   // 32

    // ---- prologue: stage kt=0 into buf0 ----
    {
        float4 v = *(const float4*)ag;            // issued first -> vmcnt(4) wait
        #pragma unroll
        for (int i = 0; i < 4; ++i)
            gload_lds16(bg[i], &sm.t[b_off[i]]);
        ssq += v.x * v.x + v.y * v.y + v.z * v.z + v.w * v.w;
        u16x4 u;
        u[0] = __builtin_bit_cast(unsigned short, __float2bfloat16(v.x));
        u[1] = __builtin_bit_cast(unsigned short, __float2bfloat16(v.y));
        u[2] = __builtin_bit_cast(unsigned short, __float2bfloat16(v.z));
        u[3] = __builtin_bit_cast(unsigned short, __float2bfloat16(v.w));
        *(u16x4*)&sm.t[a_woff] = u;
    }

    for (int kt = 0; kt < nK; ++kt) {
        __syncthreads();   // buf[kt] staged & visible; buf[kt+1] free
        unsigned short* cur = &sm.t[(kt & 1) * BUFSZ];
        unsigned short* nxt = &sm.t[((kt + 1) & 1) * BUFSZ];

        float4 v;
        const bool has_next = (kt + 1) < nK;
        if (has_next) {
            v = *(const float4*)(ag + (kt + 1) * BK);   // A prefetch (oldest vm op)
            #pragma unroll
            for (int i = 0; i < 4; ++i)
                gload_lds16(bg[i] + (kt + 1) * BK, nxt + b_off[i]);
        }

        bf16x8 af[4], bfv[4];
        #pragma unroll
        for (int mt = 0; mt < 4; ++mt) af[mt] = *(const bf16x8*)(cur + a_roff[mt]);
        #pragma unroll
        for (int i = 0; i < 4; ++i)    bfv[i] = *(const bf16x8*)(cur + b_roff[i]);
        #pragma unroll
        for (int mt = 0; mt < 4; ++mt)
            #pragma unroll
            for (int nt = 0; nt < 4; ++nt)
                acc[mt][nt] = __builtin_amdgcn_mfma_f32_16x16x32_bf16(
                    af[mt], bfv[nt], acc[mt][nt], 0, 0, 0);

        if (has_next) {   // A-load latency hidden behind the MFMA block
            ssq += v.x * v.x + v.y * v.y + v.z * v.z + v.w * v.w;
            u16x4 u;
            u[0] = __builtin_bit_cast(unsigned short, __float2bfloat16(v.x));
            u[1] = __builtin_bit_cast(unsigned short, __float2bfloat16(v.y));
            u[2] = __builtin_bit_cast(unsigned short, __float2bfloat16(v.z));
            u[3] = __builtin_bit_cast(unsigned short, __float2bfloat16(v.w));
            *(u16x4*)(nxt + a_woff) = u;
        }
    }

    // ---- row inverse norms: reduce 8 k-slice partials per row ----
    ssq += __shfl_xor(ssq, 1);
    ssq += __shfl_xor(ssq, 2);
    ssq += __shfl_xor(ssq, 4);
    if (aj == 0) inv_e_s[ar] = 1.0f / fmaxf(sqrtf(ssq), EPS);

    // ---- epilogue: scale + per-16-row logsumexp + NLL ----
    float ic[4];
    #pragma unroll
    for (int nt = 0; nt < 4; ++nt)
        ic[nt] = inv_c[wave * 64 + nt * 16 + tq];
    const float invN = 1.0f / (float)N;

    for (int g = 0; g < 4; ++g) {
        __syncthreads();
        float ie[4];
        #pragma unroll
        for (int r = 0; r < 4; ++r)
            ie[r] = inv_e_s[g * 16 + quad * 4 + r];
        #pragma unroll
        for (int nt = 0; nt < 4; ++nt) {
            int col = wave * 64 + nt * 16 + tq;
            #pragma unroll
            for (int r = 0; r < 4; ++r)
                sm.L[(quad * 4 + r) * LSTRIDE + col] = acc[g][nt][r] * ie[r] * ic[nt];
        }
        __syncthreads();
        #pragma unroll
        for (int rr = 0; rr < 2; ++rr) {
            int rl = wave * 2 + rr;
            int grow = blockRow + g * 16 + rl;
            float vals[8];
            float vmax = -3.0e38f;
            #pragma unroll
            for (int j = 0; j < 8; ++j) {
                vals[j] = sm.L[rl * LSTRIDE + j * 64 + lane];
                vmax = fmaxf(vmax, vals[j]);
            }
            #pragma unroll
            for (int off = 32; off; off >>= 1) vmax = fmaxf(vmax, __shfl_xor(vmax, off));
            float s = 0.0f;
            #pragma unroll
            for (int j = 0; j < 8; ++j) s += __expf(vals[j] - vmax);
            #pragma unroll
            for (int off = 32; off; off >>= 1) s += __shfl_xor(s, off);
            if (lane == 0) {
                int lab = labels[grow];
                float ll = sm.L[rl * LSTRIDE + lab];
                atomicAdd(&blockLoss, vmax + __logf(s) - ll);
            }
        }
    }
    __syncthreads();
    if (tid == 0) atomicAdd(out, blockLoss * invN);
}

// ---------------------------------------------------------------------------
extern "C" void kernel_launch(void* const* d_in, const int* in_sizes, int n_in,
                              void* d_out, int out_size, void* d_ws, size_t ws_size,
                              hipStream_t stream)
{
    const float* emb = (const float*)d_in[0];
    const float* cen = (const float*)d_in[1];
    const int* labels = (const int*)d_in[2];
    float* out = (float*)d_out;

    const int N = in_sizes[2];
    const int D = in_sizes[0] / N;
    const int K = in_sizes[1] / D;

    char* ws = (char*)d_ws;
    unsigned short* Bbf = (unsigned short*)ws;              // K*D*2 bytes
    float* inv_c = (float*)(ws + (size_t)K * D * 2);        // K floats

    hipMemsetAsync(d_out, 0, sizeof(float), stream);

    prep_centers_kernel<<<(K + 3) / 4, 256, 0, stream>>>(cen, Bbf, inv_c, K, D);

    gemm_loss_kernel<<<N / BM, 512, 0, stream>>>(emb, Bbf, inv_c, labels, out, N, D);
}

// Round 4
// 414.154 us; speedup vs baseline: 1.4255x; 1.1716x over previous
//
#include <hip/hip_runtime.h>
#include <hip/hip_bf16.h>

typedef __bf16 bf16x8 __attribute__((ext_vector_type(8)));
typedef float f32x4 __attribute__((ext_vector_type(4)));
typedef unsigned short u16x4 __attribute__((ext_vector_type(4)));
typedef unsigned short u16x8 __attribute__((ext_vector_type(8)));

#define EPS 1e-8f
#define TAU_INV 10.0f

#define BM 64
#define BN 512
#define BK 32
#define LSTRIDE 516    // 512 + 4 pad for epilogue fp32 tile

#define ABUF 2048                // u16: 4 tiles * 64 granules * 8
#define BBUF 16384               // u16: 32 tiles * 512
#define BUFSZ (ABUF + BBUF)      // 18432 u16 = 36 KB per buffer
#define BSTEP 16384              // u16 per kt-block in swizzled B (32 tiles * 512)

// async global->LDS, 16B per lane, dest = wave-uniform base + lane*16
__device__ __forceinline__ void gload_lds16(const void* g, void* l) {
    __builtin_amdgcn_global_load_lds(
        (const __attribute__((address_space(1))) void*)g,
        (__attribute__((address_space(3))) void*)l,
        16, 0, 0);
}

// ---------------------------------------------------------------------------
// prep: centers -> bf16 in MFMA-granule-swizzled order + inv norms.
// Bsw layout: granule g = 16B at ((kt*32 + nt)*64 + (r&15) + q*16)*8 u16,
// holding B[r][kt*32 + q*8 .. +8]. One wave per row; lane i owns k=i*16..+16.
// ---------------------------------------------------------------------------
__global__ __launch_bounds__(256) void prep_centers_kernel(
    const float* __restrict__ cen, unsigned short* __restrict__ Bsw,
    float* __restrict__ inv_c, int K, int D)
{
    const int wave = threadIdx.x >> 6;
    const int lane = threadIdx.x & 63;
    const int row  = blockIdx.x * 4 + wave;
    if (row >= K) return;

    const float* src = cen + (size_t)row * D + lane * 16;
    const int kt = lane >> 1;          // k-block of this lane's 16 elements
    const int nt = row >> 4;
    const int r16 = row & 15;
    const int q0 = (lane & 1) * 2;     // quad of first 8 elements

    float ss = 0.0f;
    u16x8 g[2];
    #pragma unroll
    for (int h = 0; h < 2; ++h) {
        #pragma unroll
        for (int j = 0; j < 2; ++j) {
            float4 v = *(const float4*)(src + h * 8 + j * 4);
            ss += v.x * v.x + v.y * v.y + v.z * v.z + v.w * v.w;
            g[h][j * 4 + 0] = __builtin_bit_cast(unsigned short, __float2bfloat16(v.x));
            g[h][j * 4 + 1] = __builtin_bit_cast(unsigned short, __float2bfloat16(v.y));
            g[h][j * 4 + 2] = __builtin_bit_cast(unsigned short, __float2bfloat16(v.z));
            g[h][j * 4 + 3] = __builtin_bit_cast(unsigned short, __float2bfloat16(v.w));
        }
        size_t off = ((size_t)(kt * 32 + nt) * 64 + r16 + (q0 + h) * 16) * 8;
        *(u16x8*)(Bsw + off) = g[h];
    }
    #pragma unroll
    for (int off = 32; off; off >>= 1) ss += __shfl_xor(ss, off);
    if (lane == 0)
        inv_c[row] = (1.0f / fmaxf(sqrtf(ss), EPS)) * TAU_INV; // fold 1/tau
}

// ---------------------------------------------------------------------------
// fused GEMM + log-softmax + NLL, double-buffered LDS, 1 barrier per K-step.
// block = 64 rows x all 512 centers; 512 threads = 8 waves.
// B reads are wave-contiguous 1KB DMAs thanks to the swizzled layout.
// ---------------------------------------------------------------------------
__global__ __launch_bounds__(512, 4) void gemm_loss_kernel(
    const float* __restrict__ Afp, const unsigned short* __restrict__ Bsw,
    const float* __restrict__ inv_c, const int* __restrict__ labels,
    float* __restrict__ out, int N, int D)
{
    __shared__ union {
        unsigned short t[2 * BUFSZ];   // [buf][A(4KB) | B(32KB)]
        float L[16 * LSTRIDE];         // epilogue overlay (33 KB)
    } sm;
    __shared__ float inv_e_s[BM];
    __shared__ float blockLoss;

    const int tid  = threadIdx.x;
    const int wave = tid >> 6;
    const int lane = tid & 63;
    const int quad = lane >> 4;
    const int tq   = lane & 15;
    const int blockRow = blockIdx.x * BM;

    // ---- A staging map: thread owns (row=tid>>3, float4 slice aj=tid&7) ----
    const int ar   = tid >> 3;        // 0..63
    const int aj   = tid & 7;         // 0..7
    const int a_mt = ar >> 4, a_r16 = ar & 15;
    const int a_q  = aj >> 1, a_jl = aj & 1;
    const int a_woff = a_mt * 512 + ((a_r16 ^ (2 * a_q)) + a_q * 16) * 8 + a_jl * 4;
    const float* ag = Afp + (size_t)(blockRow + ar) * D + aj * 4;

    // ---- B staging: wave w DMAs its 4 nt-tiles; contiguous 1KB per instr ----
    const unsigned short* bg[4];
    int b_off[4];
    #pragma unroll
    for (int i = 0; i < 4; ++i) {
        int nt = wave * 4 + i;
        bg[i]    = Bsw + (size_t)nt * 512 + lane * 8;   // + kt*BSTEP per iter
        b_off[i] = ABUF + nt * 512;                     // wave-uniform LDS base
    }

    // ---- fragment read offsets (buffer-relative, kt-invariant) ----
    const int a_rslot = (tq ^ (2 * quad)) + quad * 16;
    int a_roff[4], b_roff[4];
    #pragma unroll
    for (int mt = 0; mt < 4; ++mt) a_roff[mt] = mt * 512 + a_rslot * 8;
    #pragma unroll
    for (int i = 0; i < 4; ++i)    b_roff[i]  = ABUF + (wave * 4 + i) * 512 + lane * 8;

    f32x4 acc[4][4];
    #pragma unroll
    for (int mt = 0; mt < 4; ++mt)
        #pragma unroll
        for (int nt = 0; nt < 4; ++nt)
            acc[mt][nt] = (f32x4){0.f, 0.f, 0.f, 0.f};
    float ssq = 0.0f;
    if (tid == 0) blockLoss = 0.0f;

    const int nK = D / BK;   // 32

    // ---- prologue: stage kt=0 into buf0 ----
    {
        float4 v = *(const float4*)ag;            // issued first
        #pragma unroll
        for (int i = 0; i < 4; ++i)
            gload_lds16(bg[i], &sm.t[b_off[i]]);
        ssq += v.x * v.x + v.y * v.y + v.z * v.z + v.w * v.w;
        u16x4 u;
        u[0] = __builtin_bit_cast(unsigned short, __float2bfloat16(v.x));
        u[1] = __builtin_bit_cast(unsigned short, __float2bfloat16(v.y));
        u[2] = __builtin_bit_cast(unsigned short, __float2bfloat16(v.z));
        u[3] = __builtin_bit_cast(unsigned short, __float2bfloat16(v.w));
        *(u16x4*)&sm.t[a_woff] = u;
    }

    for (int kt = 0; kt < nK; ++kt) {
        __syncthreads();   // buf[kt] staged & visible; buf[kt+1] free
        unsigned short* cur = &sm.t[(kt & 1) * BUFSZ];
        unsigned short* nxt = &sm.t[((kt + 1) & 1) * BUFSZ];

        float4 v;
        const bool has_next = (kt + 1) < nK;
        if (has_next) {
            v = *(const float4*)(ag + (kt + 1) * BK);   // A prefetch (oldest vm op)
            #pragma unroll
            for (int i = 0; i < 4; ++i)
                gload_lds16(bg[i] + (size_t)(kt + 1) * BSTEP, nxt + b_off[i]);
        }

        bf16x8 af[4], bfv[4];
        #pragma unroll
        for (int mt = 0; mt < 4; ++mt) af[mt] = *(const bf16x8*)(cur + a_roff[mt]);
        #pragma unroll
        for (int i = 0; i < 4; ++i)    bfv[i] = *(const bf16x8*)(cur + b_roff[i]);
        #pragma unroll
        for (int mt = 0; mt < 4; ++mt)
            #pragma unroll
            for (int nt = 0; nt < 4; ++nt)
                acc[mt][nt] = __builtin_amdgcn_mfma_f32_16x16x32_bf16(
                    af[mt], bfv[nt], acc[mt][nt], 0, 0, 0);

        if (has_next) {   // A-load latency hidden behind the MFMA block
            ssq += v.x * v.x + v.y * v.y + v.z * v.z + v.w * v.w;
            u16x4 u;
            u[0] = __builtin_bit_cast(unsigned short, __float2bfloat16(v.x));
            u[1] = __builtin_bit_cast(unsigned short, __float2bfloat16(v.y));
            u[2] = __builtin_bit_cast(unsigned short, __float2bfloat16(v.z));
            u[3] = __builtin_bit_cast(unsigned short, __float2bfloat16(v.w));
            *(u16x4*)(nxt + a_woff) = u;
        }
    }

    // ---- row inverse norms: reduce 8 k-slice partials per row ----
    ssq += __shfl_xor(ssq, 1);
    ssq += __shfl_xor(ssq, 2);
    ssq += __shfl_xor(ssq, 4);
    if (aj == 0) inv_e_s[ar] = 1.0f / fmaxf(sqrtf(ssq), EPS);

    // ---- epilogue: scale + per-16-row logsumexp + NLL ----
    float ic[4];
    #pragma unroll
    for (int nt = 0; nt < 4; ++nt)
        ic[nt] = inv_c[wave * 64 + nt * 16 + tq];
    const float invN = 1.0f / (float)N;

    for (int g = 0; g < 4; ++g) {
        __syncthreads();
        float ie[4];
        #pragma unroll
        for (int r = 0; r < 4; ++r)
            ie[r] = inv_e_s[g * 16 + quad * 4 + r];
        #pragma unroll
        for (int nt = 0; nt < 4; ++nt) {
            int col = wave * 64 + nt * 16 + tq;
            #pragma unroll
            for (int r = 0; r < 4; ++r)
                sm.L[(quad * 4 + r) * LSTRIDE + col] = acc[g][nt][r] * ie[r] * ic[nt];
        }
        __syncthreads();
        #pragma unroll
        for (int rr = 0; rr < 2; ++rr) {
            int rl = wave * 2 + rr;
            int grow = blockRow + g * 16 + rl;
            float vals[8];
            float vmax = -3.0e38f;
            #pragma unroll
            for (int j = 0; j < 8; ++j) {
                vals[j] = sm.L[rl * LSTRIDE + j * 64 + lane];
                vmax = fmaxf(vmax, vals[j]);
            }
            #pragma unroll
            for (int off = 32; off; off >>= 1) vmax = fmaxf(vmax, __shfl_xor(vmax, off));
            float s = 0.0f;
            #pragma unroll
            for (int j = 0; j < 8; ++j) s += __expf(vals[j] - vmax);
            #pragma unroll
            for (int off = 32; off; off >>= 1) s += __shfl_xor(s, off);
            if (lane == 0) {
                int lab = labels[grow];
                float ll = sm.L[rl * LSTRIDE + lab];
                atomicAdd(&blockLoss, vmax + __logf(s) - ll);
            }
        }
    }
    __syncthreads();
    if (tid == 0) atomicAdd(out, blockLoss * invN);
}

// ---------------------------------------------------------------------------
extern "C" void kernel_launch(void* const* d_in, const int* in_sizes, int n_in,
                              void* d_out, int out_size, void* d_ws, size_t ws_size,
                              hipStream_t stream)
{
    const float* emb = (const float*)d_in[0];
    const float* cen = (const float*)d_in[1];
    const int* labels = (const int*)d_in[2];
    float* out = (float*)d_out;

    const int N = in_sizes[2];
    const int D = in_sizes[0] / N;
    const int K = in_sizes[1] / D;

    char* ws = (char*)d_ws;
    unsigned short* Bsw = (unsigned short*)ws;              // K*D*2 bytes, swizzled
    float* inv_c = (float*)(ws + (size_t)K * D * 2);        // K floats

    hipMemsetAsync(d_out, 0, sizeof(float), stream);

    prep_centers_kernel<<<(K + 3) / 4, 256, 0, stream>>>(cen, Bsw, inv_c, K, D);

    gemm_loss_kernel<<<N / BM, 512, 0, stream>>>(emb, Bsw, inv_c, labels, out, N, D);
}